// Round 7
// baseline (540.860 us; speedup 1.0000x reference)
//
#include <hip/hip_runtime.h>

// out[e,i] = sum_j mat[e,i,j] v[e,j] + bias[e,i],  [mat|bias] = MLP(pos).reshape(32,33)
// R7 = R6 occupancy plan (512 thr / 8 waves, EPB=512, NBLK=512 = 2 blocks/CU, 4 waves/SIMD,
// vt bf16) with the R5 chunk geometry restored: PERMUTED ih-major tile order, 22 chunks x
// 3 tiles (12288 B), g_chunk<IH> template, staging 12x1KB DMA == chunk size == Bb buffer.
// P[e,col] = h2[e,:128] @ Wpack[:,col] via MFMA, A(h2)-frags VGPR-resident; einsum fused
// as per-tile FMA vs LDS vt (bf16); b3 folded via mini-GEMM C-init.
// ws: Wg2 @0 (270336 B), W2f @270336 (32768), b3f @303104 (2048), b3c @305152 (128)

#define E_TOTAL 262144
#define EPB 512
#define NBLK (E_TOTAL / EPB)

typedef float f32x4 __attribute__((ext_vector_type(4)));
typedef short s8v  __attribute__((ext_vector_type(8)));

__device__ __forceinline__ unsigned short f2bf(float x) {
  unsigned u = __float_as_uint(x);
  u += 0x7fffu + ((u >> 16) & 1u);
  return (unsigned short)(u >> 16);
}

__device__ __forceinline__ void gld16(const void* g, void* l) {
  __builtin_amdgcn_global_load_lds(
      (const __attribute__((address_space(1))) unsigned int*)g,
      (__attribute__((address_space(3))) unsigned int*)l, 16, 0, 0);
}

// ---------------- prep: pack W2/W3/b3 into MFMA B-fragment order ----------------
__global__ void prep_pack(const float* __restrict__ W2, const float* __restrict__ W3,
                          const float* __restrict__ b3,
                          unsigned short* __restrict__ Wg2, unsigned short* __restrict__ W2f,
                          unsigned short* __restrict__ b3f, float* __restrict__ b3c) {
  int idx = blockIdx.x * 256 + threadIdx.x;   // 528 blocks cover 135168
  if (idx < 135168) {
    // Wg2[((nn*4+ks)*64 + lane)*8 + jj] : B[k=ks*32+(lane>>4)*8+jj][col=nnt*16+(lane&15)]
    // PERMUTED (ih-major) tile order: nn<33 -> nnt=2*nn (ih=0, j=nn); else nnt=2*(nn-33)+1
    int jj = idx & 7, lane = (idx >> 3) & 63;
    int ksnn = idx >> 9, ks = ksnn & 3, nn = ksnn >> 2;
    int nnt = (nn < 33) ? (2 * nn) : (2 * (nn - 33) + 1);
    int k = ks * 32 + ((lane >> 4) << 3) + jj;
    int col = nnt * 16 + (lane & 15);        // col = j*32 + i
    int i = col & 31, j = col >> 5;
    Wg2[idx] = f2bf(W3[k * 1056 + i * 33 + j]);
  }
  if (idx < 16384) {
    int ks = idx >> 12, nt = (idx >> 9) & 7, l = (idx >> 3) & 63, jj = idx & 7;
    int k = ks * 32 + ((l >> 4) << 3) + jj;
    int n = nt * 16 + (l & 15);
    W2f[idx] = f2bf(W2[k * 128 + n]);
  }
  if (idx < 1024) {
    int jj = idx & 7, lane = (idx >> 3) & 63, ih = idx >> 9;
    int j = ((lane >> 4) << 3) + jj, i = ih * 16 + (lane & 15);
    b3f[idx] = f2bf(b3[i * 33 + j]);
  }
  if (idx < 32) b3c[idx] = b3[idx * 33 + 32];
}

// ---------------- G-loop chunk body (IH compile-time: out-acc half) ----------------
template <int IH>
__device__ __forceinline__ void g_chunk(const unsigned short* __restrict__ buf,
                                        const unsigned short* __restrict__ vt,
                                        int j0, int lane, int eoff,
                                        const s8v (&af)[4][4], float (&oa)[2][4][4]) {
  const f32x4 zero4 = {0.f, 0.f, 0.f, 0.f};
#pragma unroll
  for (int t = 0; t < 3; ++t) {
    const int j = j0 + t;
    f32x4 p[4];
#pragma unroll
    for (int ks = 0; ks < 4; ++ks) {
      s8v bfr = *(const s8v*)&buf[(t * 4 + ks) * 512 + lane * 8];
#pragma unroll
      for (int m = 0; m < 4; ++m)
        p[m] = __builtin_amdgcn_mfma_f32_16x16x32_bf16(
            af[m][ks], bfr, (ks == 0 ? zero4 : p[m]), 0, 0, 0);
    }
#pragma unroll
    for (int m = 0; m < 4; ++m) {
      uint2 hv = *(const uint2*)&vt[j * 520 + eoff + m * 16];
      oa[IH][m][0] += __uint_as_float(hv.x << 16) * p[m][0];
      oa[IH][m][1] += __uint_as_float(hv.x & 0xffff0000u) * p[m][1];
      oa[IH][m][2] += __uint_as_float(hv.y << 16) * p[m][2];
      oa[IH][m][3] += __uint_as_float(hv.y & 0xffff0000u) * p[m][3];
    }
  }
}

// ---------------- fused main kernel ----------------
// 512 threads (8 waves), 512 edges/block; wave w owns edges [B0+w*64, B0+w*64+64).
// LDS 69632 B: transient h1c u16[128][136] @0 (34816), h2n u16[128][136] @34816;
// then vt u16[33][520] @0 (34320) + Bb u16[2][6144] @34816 (24576 B).
// 2 blocks/CU -> 16 waves/CU -> 4 waves/SIMD.
__global__ __launch_bounds__(512, 4) void fnn_fused(
    const float* __restrict__ pos_i, const float* __restrict__ pos_j,
    const float* __restrict__ vj, const float* __restrict__ W1,
    const float* __restrict__ b1, const float* __restrict__ b2,
    const unsigned short* __restrict__ W2f, const unsigned short* __restrict__ Wg2,
    const unsigned short* __restrict__ b3f, const float* __restrict__ b3c,
    float* __restrict__ out) {
  __shared__ __attribute__((aligned(16))) char smem[69632];
  unsigned short* vt  = (unsigned short*)smem;            // [33][520] bf16
  unsigned short* h1c = (unsigned short*)smem;            // [128][136] transient
  unsigned short* h2n = (unsigned short*)(smem + 34816);  // [128][136] transient
  unsigned short* Bb  = (unsigned short*)(smem + 34816);  // [2][6144]

  const int tid = threadIdx.x;
  const int w = tid >> 6, lane = tid & 63, q = lane >> 4, ln = lane & 15;
  const int B0 = blockIdx.x * EPB;
  const int eoff = w * 64 + q * 4;

  // --- out-acc init via b3 mini-GEMM: oa[ih][m][r] = sum_j v[e,j] b3[i*33+j] + b3[i*33+32] ---
  float oa[2][4][4];
  {
    s8v av[4];
#pragma unroll
    for (int m = 0; m < 4; ++m) {
      int e = B0 + w * 64 + m * 16 + ln;
      const float4 va = *(const float4*)(vj + (size_t)e * 32 + q * 8);
      const float4 vb = *(const float4*)(vj + (size_t)e * 32 + q * 8 + 4);
      s8v t;
      t[0] = (short)f2bf(va.x); t[1] = (short)f2bf(va.y);
      t[2] = (short)f2bf(va.z); t[3] = (short)f2bf(va.w);
      t[4] = (short)f2bf(vb.x); t[5] = (short)f2bf(vb.y);
      t[6] = (short)f2bf(vb.z); t[7] = (short)f2bf(vb.w);
      av[m] = t;
    }
#pragma unroll
    for (int ih = 0; ih < 2; ++ih) {
      s8v b3fr = *(const s8v*)(b3f + (ih * 64 + lane) * 8);
      float cbv = b3c[ih * 16 + ln];
      f32x4 ci = {cbv, cbv, cbv, cbv};
#pragma unroll
      for (int m = 0; m < 4; ++m) {
        f32x4 p = __builtin_amdgcn_mfma_f32_16x16x32_bf16(av[m], b3fr, ci, 0, 0, 0);
#pragma unroll
        for (int r = 0; r < 4; ++r) oa[ih][m][r] = p[r];
      }
    }
  }

  // --- W1/b1 register slices ---
  const int hh0 = (tid & 15) * 8;
  float w1r[4][8], b1r[8];
#pragma unroll
  for (int d = 0; d < 4; ++d)
#pragma unroll
    for (int u = 0; u < 8; ++u) w1r[d][u] = W1[d * 128 + hh0 + u];
#pragma unroll
  for (int u = 0; u < 8; ++u) b1r[u] = b1[hh0 + u];

  // --- stages 1+2 per qtr (128 edges); waves 2q,2q+1 extract their A-frags ---
  s8v af[4][4];
  for (int qtr = 0; qtr < 4; ++qtr) {
#pragma unroll
    for (int half = 0; half < 4; ++half) {
      int ee = (tid >> 4) + half * 32;       // 0..127
      int eg = B0 + qtr * 128 + ee;
      float2 pi = *(const float2*)(pos_i + (size_t)eg * 2);
      float2 pj = *(const float2*)(pos_j + (size_t)eg * 2);
      s8v hv;
#pragma unroll
      for (int u = 0; u < 8; ++u) {
        float o = b1r[u] + pi.x * w1r[0][u] + pi.y * w1r[1][u] +
                  pj.x * w1r[2][u] + pj.y * w1r[3][u];
        hv[u] = (short)f2bf(fmaxf(o, 0.f));
      }
      *(s8v*)&h1c[ee * 136 + hh0] = hv;
    }
    __syncthreads();
    {
      s8v afr[4];
#pragma unroll
      for (int ks = 0; ks < 4; ++ks)
        afr[ks] = *(const s8v*)&h1c[(w * 16 + ln) * 136 + ks * 32 + q * 8];
#pragma unroll
      for (int nt = 0; nt < 8; ++nt) {
        f32x4 a4 = {0.f, 0.f, 0.f, 0.f};
#pragma unroll
        for (int ks = 0; ks < 4; ++ks) {
          s8v bfr2 = *(const s8v*)(W2f + ((ks * 8 + nt) * 64 + lane) * 8);
          a4 = __builtin_amdgcn_mfma_f32_16x16x32_bf16(afr[ks], bfr2, a4, 0, 0, 0);
        }
        float b2v = b2[nt * 16 + ln];
#pragma unroll
        for (int r = 0; r < 4; ++r)
          h2n[(w * 16 + q * 4 + r) * 136 + nt * 16 + ln] =
              f2bf(fmaxf(a4[r] + b2v, 0.f));
      }
    }
    __syncthreads();
    if ((w >> 1) == qtr) {
#pragma unroll
      for (int m = 0; m < 4; ++m)
#pragma unroll
        for (int ks = 0; ks < 4; ++ks)
          af[m][ks] = *(const s8v*)&h2n[((w & 1) * 64 + m * 16 + ln) * 136 + ks * 32 + q * 8];
    }
    // extraction overlaps next stage-1 (h1c disjoint from h2n); pre-stage-2 barrier protects
  }
  __syncthreads();   // drain last h2n reads before vt/Bb overlay

  // --- build vt (bf16): vt[j][e] = v[e,j], row 32 = 1.0 ---
  {
    const float* vrow = vj + (size_t)(B0 + tid) * 32;
#pragma unroll
    for (int j4 = 0; j4 < 8; ++j4) {
      float4 vv = *(const float4*)(vrow + j4 * 4);
      vt[(j4 * 4 + 0) * 520 + tid] = f2bf(vv.x);
      vt[(j4 * 4 + 1) * 520 + tid] = f2bf(vv.y);
      vt[(j4 * 4 + 2) * 520 + tid] = f2bf(vv.z);
      vt[(j4 * 4 + 3) * 520 + tid] = f2bf(vv.w);
    }
    vt[32 * 520 + tid] = 0x3F80;
  }
  __syncthreads();

  // --- preload B chunk 0 via LDS-DMA: 12288 B = 12 units of 1 KB across 8 waves ---
#pragma unroll 2
  for (int u = w; u < 12; u += 8)
    gld16((const char*)Wg2 + u * 1024 + lane * 16, (char*)Bb + u * 1024);
  __syncthreads();

  // --- G-loop: 22 chunks x 3 tiles (12288 B each), double-buffered DMA staging ---
  for (int c = 0; c < 22; ++c) {
    const unsigned short* buf = Bb + (c & 1) * 6144;
    if (c + 1 < 22) {
      const char* g = (const char*)Wg2 + (c + 1) * 12288;
      char* l = (char*)Bb + ((c + 1) & 1) * 12288;
#pragma unroll 2
      for (int u = w; u < 12; u += 8)
        gld16(g + u * 1024 + lane * 16, l + u * 1024);
    }
    if (c < 11) g_chunk<0>(buf, vt, c * 3, lane, eoff, af, oa);
    else        g_chunk<1>(buf, vt, (c - 11) * 3, lane, eoff, af, oa);
    __syncthreads();
  }

  // --- epilogue: out[e,i] f32 ---
#pragma unroll
  for (int m = 0; m < 4; ++m)
#pragma unroll
    for (int ih = 0; ih < 2; ++ih)
#pragma unroll
      for (int r = 0; r < 4; ++r) {
        int e = B0 + w * 64 + m * 16 + q * 4 + r;
        out[(size_t)e * 32 + ih * 16 + ln] = oa[ih][m][r];
      }
}

extern "C" void kernel_launch(void* const* d_in, const int* in_sizes, int n_in,
                              void* d_out, int out_size, void* d_ws, size_t ws_size,
                              hipStream_t stream) {
  const float* pos_i = (const float*)d_in[0];
  const float* pos_j = (const float*)d_in[1];
  const float* vj    = (const float*)d_in[2];
  const float* W1    = (const float*)d_in[3];
  const float* b1    = (const float*)d_in[4];
  const float* W2    = (const float*)d_in[5];
  const float* b2    = (const float*)d_in[6];
  const float* W3    = (const float*)d_in[7];
  const float* b3    = (const float*)d_in[8];
  float* outp = (float*)d_out;

  unsigned short* Wg2 = (unsigned short*)d_ws;
  unsigned short* W2f = (unsigned short*)((char*)d_ws + 270336);
  unsigned short* b3f = (unsigned short*)((char*)d_ws + 303104);
  float*          b3c = (float*)((char*)d_ws + 305152);

  prep_pack<<<528, 256, 0, stream>>>(W2, W3, b3, Wg2, W2f, b3f, b3c);
  fnn_fused<<<NBLK, 512, 0, stream>>>(pos_i, pos_j, vj, W1, b1, b2, W2f, Wg2, b3f, b3c, outp);
}